// Round 7
// baseline (7599.271 us; speedup 1.0000x reference)
//
#include <hip/hip_runtime.h>
#include <stdint.h>

typedef unsigned short u16;
typedef unsigned int   u32;

// problem dims
#define TB_ 8      // batch
#define NN_ 256    // state n
#define DD_ 684    // context depth d
#define PP_ 576    // H*W = 12*48

// workspace offsets (bytes)
#define OFF_PCTX 0u          // f32 [b][j(16)][p(576)][ai(32)]  (pctx + UaC_b + UfC_b folded)
#define OFF_SB   9437184u    // f32  [g(3)][t(32)][b(8)][n(256)]
#define OFF_FKT  10223616u   // f32  [tap(9)][a(512)]
#define OFF_BUF  10242048u   // f32  [32][b][684]  (ctC history; entry e written at step e-1)
#define OFF_RAWP 10942464u   // f32  [b][j(16)][p(576)] partial raw alpha
#define OFF_H    11237376u   // f32  [b][n] initial h state
#define OFF_H0   11245568u   // f32  [b][n] h0 of current step
#define OFF_AP   11253760u   // f32  [b][p] coverage accumulator
#define OFF_QWS  11272192u   // f32  [b][a(512)] query
#define OFF_FLG  11288576u   // int  dtype flag (1 = inputs are f32, 0 = bf16)
#define WS_NEED  11288592u

// output offsets (elements, f32 — reference output dtype is float32)
#define OFF_H2   0
#define OFF_CTC  65536
#define OFF_CTP  240640
#define OFF_AL   415744
#define OFF_APO  563200

__device__ __forceinline__ float bl(u32 v){ union{u32 i; float f;} x; x.i = v<<16; return x.f; }
__device__ __forceinline__ float bh(u32 v){ union{u32 i; float f;} x; x.i = v & 0xFFFF0000u; return x.f; }
__device__ __forceinline__ float b2f(u16 v){ union{u32 i; float f;} x; x.i = ((u32)v)<<16; return x.f; }

// dual-dtype scalar load: input tensor is f32 (flag=1) or bf16 (flag=0)
__device__ __forceinline__ float gld(const void* p, size_t i, int f32){
  if (f32) return ((const float*)p)[i];
  return b2f(((const u16*)p)[i]);
}

__device__ __forceinline__ float rcpf(float x){ return __builtin_amdgcn_rcpf(x); }
__device__ __forceinline__ float sigm(float x){
  x = fminf(fmaxf(x, -30.f), 30.f);
  return rcpf(1.f + __expf(-x));
}
__device__ __forceinline__ float tanh_c(float x){
  x = fminf(fmaxf(x, -15.f), 15.f);
  float e = __expf(2.f*x);
  return 1.f - 2.f*rcpf(e + 1.f);
}

// dot of 8 bf16 (packed uint4) with 8 consecutive floats
__device__ __forceinline__ float dot8(uint4 u, const float* s){
  float a = fmaf(bl(u.x), s[0], bh(u.x)*s[1]);
  a = fmaf(bl(u.y), s[2], a); a = fmaf(bh(u.y), s[3], a);
  a = fmaf(bl(u.z), s[4], a); a = fmaf(bh(u.z), s[5], a);
  a = fmaf(bl(u.w), s[6], a); a = fmaf(bh(u.w), s[7], a);
  return a;
}
__device__ __forceinline__ float dot4(uint2 u, const float* s, float a){
  a = fmaf(bl(u.x), s[0], a); a = fmaf(bh(u.x), s[1], a);
  a = fmaf(bl(u.y), s[2], a); a = fmaf(bh(u.y), s[3], a);
  return a;
}
// f32-row dot: w 16B-aligned, n multiple of 4
__device__ __forceinline__ float dotf(const float* w, const float* s, int n){
  float a = 0.f;
  #pragma unroll 4
  for (int k=0;k<n;k+=4){
    float4 u = *(const float4*)(w+k);
    a = fmaf(u.x, s[k], a);   a = fmaf(u.y, s[k+1], a);
    a = fmaf(u.z, s[k+2], a); a = fmaf(u.w, s[k+3], a);
  }
  return a;
}

// ---------------- dtype detector ----------------
// Samples 512 u16s of `context`. bf16 data: ~0 insane exponent fields.
// Full-mantissa f32 read as u16: even indices are mantissa bits -> ~40% insane.
__global__ void k_detect(const u16* __restrict__ ctx_u16, int* __restrict__ flag){
  __shared__ int cnt;
  if (threadIdx.x == 0) cnt = 0;
  __syncthreads();
  int bad = 0;
  for (int k = threadIdx.x; k < 512; k += 256){
    u16 v = ctx_u16[k];
    int e = (v >> 7) & 0xFF;
    bool sane = (v == 0u) || (v == 0x8000u) || (e >= 102 && e <= 141);
    if (!sane) bad++;
  }
  atomicAdd(&cnt, bad);
  __syncthreads();
  if (threadIdx.x == 0) flag[0] = (cnt > 64) ? 1 : 0;
}

// ---------------- precompute kernels ----------------

__global__ __launch_bounds__(256) void k_init(float* __restrict__ buf, float* __restrict__ ap,
                                              float* __restrict__ h,
                                              const void* __restrict__ init_state,
                                              const int* __restrict__ flag){
  const int f32 = flag[0];
  int i = blockIdx.x*blockDim.x + threadIdx.x;
  int stride = gridDim.x*blockDim.x;
  for (int k=i; k<32*TB_*DD_; k+=stride) buf[k] = 0.f;
  for (int k=i; k<TB_*PP_;    k+=stride) ap[k]  = 0.f;
  for (int k=i; k<TB_*NN_;    k+=stride) h[k]   = gld(init_state, k, f32);
}

// sb[g][t][b][n] = emb(t,b) . Wy_g[n,:] + by_g[n];  grid 768 = 3*32*8, thread = n
__global__ __launch_bounds__(256) void k_sb(const void* __restrict__ remb, const void* __restrict__ re_emb,
    const void* __restrict__ Wz, const void* __restrict__ bz,
    const void* __restrict__ Wr, const void* __restrict__ br,
    const void* __restrict__ Wh, const void* __restrict__ bhh,
    float* __restrict__ sb, const int* __restrict__ flag){
  const int f32 = flag[0];
  int blk = blockIdx.x;
  int g = blk >> 8;
  int tb = blk & 255; int t = tb >> 3; int b = tb & 7;
  __shared__ float emb[512];
  int tid = threadIdx.x;
  emb[tid]     = gld(remb,   (size_t)(t*8+b)*256 + tid, f32);
  emb[tid+256] = gld(re_emb, (size_t)(t*8+b)*256 + tid, f32);
  __syncthreads();
  const void* W = (g==0?Wz:(g==1?Wr:Wh));
  const void* bias = (g==0?bz:(g==1?br:bhh));
  float acc = gld(bias, tid, f32);
  if (f32){
    acc += dotf((const float*)W + (size_t)tid*512, emb, 512);
  } else {
    const u16* row = (const u16*)W + (size_t)tid*512;
    #pragma unroll 8
    for (int k=0;k<512;k+=8) acc += dot8(*(const uint4*)(row+k), &emb[k]);
  }
  sb[(((size_t)g*32+t)*8+b)*256 + tid] = acc;
}

// FKt[tap][a] = sum_c UfC[a,c]*QC[c,tap];  grid 18
__global__ __launch_bounds__(256) void k_fk(const void* __restrict__ QC, const void* __restrict__ UfC,
                                            float* __restrict__ FKt, const int* __restrict__ flag){
  const int f32 = flag[0];
  __shared__ float qc[4608];
  int tid = threadIdx.x;
  for (int k=tid;k<4608;k+=256) qc[k] = gld(QC, k, f32);
  __syncthreads();
  int flat = blockIdx.x*256 + tid;      // < 4608
  int a = flat & 511, tap = flat >> 9;
  float acc = 0.f;
  for (int c=0;c<512;c++) acc = fmaf(gld(UfC, (size_t)a*512 + c, f32), qc[c*9+tap], acc);
  FKt[tap*512 + a] = acc;
}

// pctx[b,p,a-chunk] = context[b,:,p].UaC[a,:] + UaC_b[a] + UfC_b[a]  (stored f32)
__global__ __launch_bounds__(256) void k_pctx(const void* __restrict__ context, const void* __restrict__ UaC_w,
    const void* __restrict__ UaC_b, const void* __restrict__ UfC_b, float* __restrict__ pctxs,
    const int* __restrict__ flag){
  const int f32 = flag[0];
  int blk = blockIdx.x;
  int b = blk / 72;
  int pbase = (blk - b*72) * 8;
  __shared__ float ctx[8][DD_];
  int tid = threadIdx.x;
  for (int k=tid; k<8*DD_; k+=256){
    int pl = k / DD_, d = k - pl*DD_;
    ctx[pl][d] = gld(context, ((size_t)(b*DD_+d))*PP_ + pbase + pl, f32);
  }
  __syncthreads();
  int pl = tid & 7, ag = tid >> 3;
  int p = pbase + pl;
  float acc[16];
  #pragma unroll
  for (int i=0;i<16;i++) acc[i] = 0.f;
  if (f32){
    for (int i=0;i<16;i++)
      acc[i] = dotf((const float*)UaC_w + (size_t)(ag + i*32)*DD_, ctx[pl], DD_);
  } else {
    const u16* U = (const u16*)UaC_w;
    for (int dt=0; dt<85; dt++){
      float c0[8];
      *(float4*)&c0[0] = *(const float4*)&ctx[pl][dt*8];
      *(float4*)&c0[4] = *(const float4*)&ctx[pl][dt*8+4];
      #pragma unroll
      for (int i=0;i<16;i++){
        const u16* row = U + (size_t)(ag + i*32)*DD_ + dt*8;
        uint2 ua = ((const uint2*)row)[0];
        uint2 ub = ((const uint2*)row)[1];
        acc[i] = fmaf(bl(ua.x), c0[0], acc[i]); acc[i] = fmaf(bh(ua.x), c0[1], acc[i]);
        acc[i] = fmaf(bl(ua.y), c0[2], acc[i]); acc[i] = fmaf(bh(ua.y), c0[3], acc[i]);
        acc[i] = fmaf(bl(ub.x), c0[4], acc[i]); acc[i] = fmaf(bh(ub.x), c0[5], acc[i]);
        acc[i] = fmaf(bl(ub.y), c0[6], acc[i]); acc[i] = fmaf(bh(ub.y), c0[7], acc[i]);
      }
    }
    float c0[4];
    *(float4*)&c0[0] = *(const float4*)&ctx[pl][680];
    #pragma unroll
    for (int i=0;i<16;i++){
      const u16* row = U + (size_t)(ag + i*32)*DD_ + 680;
      uint2 u = *(const uint2*)row;
      acc[i] = fmaf(bl(u.x), c0[0], acc[i]); acc[i] = fmaf(bh(u.x), c0[1], acc[i]);
      acc[i] = fmaf(bl(u.y), c0[2], acc[i]); acc[i] = fmaf(bh(u.y), c0[3], acc[i]);
    }
  }
  #pragma unroll
  for (int i=0;i<16;i++){
    int a = ag + i*32;
    pctxs[(((size_t)b*16 + i)*PP_ + p)*32 + ag] = acc[i] + gld(UaC_b, a, f32) + gld(UfC_b, a, f32);
  }
}

// ---------------- per-step kernels (no cross-block sync anywhere) ----------------

// GRU1 + query + ctP for step t. block 576.
__device__ __forceinline__ void gru1_tail(int b, int t, int f32, const float* hsrc_lds,
    const void* Uhz0, const void* Uhr0, const void* Uhh0, const void* WaC,
    const void* ly_mask, const float* sb, const int* rp, const float* buf,
    float* h0_ws, float* q_ws, float* out, float* h0_lds){
  int tid = threadIdx.x;
  if (tid < 256){
    int n = tid;
    float az, ar, ah;
    if (f32){
      az = dotf((const float*)Uhz0 + (size_t)n*256, hsrc_lds, 256);
      ar = dotf((const float*)Uhr0 + (size_t)n*256, hsrc_lds, 256);
      ah = dotf((const float*)Uhh0 + (size_t)n*256, hsrc_lds, 256);
    } else {
      const u16* rz = (const u16*)Uhz0 + (size_t)n*256;
      const u16* rr = (const u16*)Uhr0 + (size_t)n*256;
      const u16* rh = (const u16*)Uhh0 + (size_t)n*256;
      az = 0.f; ar = 0.f; ah = 0.f;
      #pragma unroll 4
      for (int k=0;k<256;k+=8){
        az += dot8(*(const uint4*)(rz+k), hsrc_lds+k);
        ar += dot8(*(const uint4*)(rr+k), hsrc_lds+k);
        ah += dot8(*(const uint4*)(rh+k), hsrc_lds+k);
      }
    }
    float lm = gld(ly_mask, t*8+b, f32);
    float hp = hsrc_lds[n];
    float z0 = sigm(az + sb[(((size_t)t)*8+b)*256 + n]);
    float r0 = sigm(ar + sb[(((size_t)(32+t))*8+b)*256 + n]);
    float hc = tanh_c(ah*r0 + sb[(((size_t)(64+t))*8+b)*256 + n]);
    float h0v = z0*hp + (1.f - z0)*hc;
    h0v = lm*h0v + (1.f - lm)*hp;
    h0_lds[n] = h0v;
    h0_ws[b*256 + n] = h0v;
  }
  __syncthreads();
  if (tid < 512){
    int a = tid;
    float acc;
    if (f32){
      acc = dotf((const float*)WaC + (size_t)a*256, h0_lds, 256);
    } else {
      const u16* wrow = (const u16*)WaC + (size_t)a*256;
      acc = 0.f;
      #pragma unroll 4
      for (int k=0;k<256;k+=8) acc += dot8(*(const uint4*)(wrow+k), h0_lds+k);
    }
    q_ws[b*512 + a] = acc;
  }
  {
    int rpos = rp[t*8+b];
    if ((unsigned)rpos > 31u) rpos = 31;
    for (int d = tid; d < DD_; d += 576){
      out[OFF_CTP + (t*8+b)*DD_ + d] = buf[((size_t)rpos*8+b)*DD_ + d];
    }
  }
}

__global__ __launch_bounds__(576, 1) void k_stepA0(
    const void* __restrict__ ly_mask,
    const void* __restrict__ Uhz0, const void* __restrict__ Uhr0, const void* __restrict__ Uhh0,
    const void* __restrict__ WaC, const int* __restrict__ rp,
    const float* __restrict__ sb, const float* __restrict__ buf, const float* __restrict__ h_ws,
    float* __restrict__ h0_ws, float* __restrict__ q_ws, float* __restrict__ out,
    const int* __restrict__ flag){
  __shared__ float h_lds[NN_];
  __shared__ float h0_lds[NN_];
  const int f32 = flag[0];
  int b = blockIdx.x, tid = threadIdx.x;
  if (tid < 256) h_lds[tid] = h_ws[b*256 + tid];
  __syncthreads();
  gru1_tail(b, 0, f32, h_lds, Uhz0, Uhr0, Uhh0, WaC, ly_mask, sb, rp, buf, h0_ws, q_ws, out, h0_lds);
}

// scores: grid 128 (b = blk>>4, j = blk&15), block 256.
__global__ __launch_bounds__(256) void k_stepB(int t,
    const float* __restrict__ pctxs, const float* __restrict__ FKt,
    const void* __restrict__ vaC_w, const float* __restrict__ q_ws,
    const float* __restrict__ ap_ws, float* __restrict__ rawp,
    const int* __restrict__ flag){
  const int f32 = flag[0];
  const int tid = threadIdx.x;
  const int b = blockIdx.x >> 4;
  const int j = blockIdx.x & 15;
  const int abase = j*32;
  __shared__ float ap_lds[PP_];
  __shared__ float fk_lds[9*32];
  __shared__ float vac_lds[32];
  __shared__ float q_lds[32];

  ap_lds[tid]       = ap_ws[b*PP_ + tid];
  ap_lds[tid + 256] = ap_ws[b*PP_ + tid + 256];
  if (tid < 64) ap_lds[tid + 512] = ap_ws[b*PP_ + tid + 512];
  if (tid < 288) fk_lds[tid] = FKt[(tid>>5)*512 + abase + (tid&31)];
  if (tid < 32){
    vac_lds[tid] = gld(vaC_w, abase + tid, f32);
    q_lds[tid]   = q_ws[b*512 + abase + tid];
  }
  __syncthreads();

  for (int rep = 0; rep < 3; rep++){
    int p = tid + rep*256;
    if (p >= PP_) break;
    float PQ[32];
    const float* pcf = pctxs + ((size_t)((b*16+j)*PP_ + p))*32;
    #pragma unroll
    for (int q8=0; q8<8; q8++){
      float4 u = *(const float4*)(pcf + q8*4);
      PQ[q8*4+0] = u.x; PQ[q8*4+1] = u.y; PQ[q8*4+2] = u.z; PQ[q8*4+3] = u.w;
    }
    int hh_ = p / 48, ww_ = p - hh_*48;
    #pragma unroll
    for (int kh=0;kh<3;kh++){
      int h2_ = hh_ + kh - 1;
      if ((unsigned)h2_ >= 12u) continue;
      #pragma unroll
      for (int kw=0;kw<3;kw++){
        int w2_ = ww_ + kw - 1;
        if ((unsigned)w2_ >= 48u) continue;
        float av = ap_lds[h2_*48 + w2_];
        const float* fkp = &fk_lds[(kh*3+kw)*32];
        #pragma unroll
        for (int ai=0;ai<32;ai++) PQ[ai] = fmaf(av, fkp[ai], PQ[ai]);
      }
    }
    float racc = 0.f;
    #pragma unroll
    for (int ai=0;ai<32;ai++)
      racc = fmaf(vac_lds[ai], tanh_c(PQ[ai] + q_lds[ai]), racc);
    rawp[((size_t)(b*16+j))*PP_ + p] = racc;
  }
}

// softmax + ctC + GRU2 (+ next step's GRU1/query/ctP). grid 8 (b), block 576.
__global__ __launch_bounds__(576, 1) void k_stepC(int t,
    const void* __restrict__ ly_mask, const void* __restrict__ context, const void* __restrict__ cmask,
    const void* __restrict__ Uhz0, const void* __restrict__ Uhr0, const void* __restrict__ Uhh0,
    const void* __restrict__ WaC, const void* __restrict__ vaC_b,
    const void* __restrict__ Uhz2, const void* __restrict__ Uhz2_b,
    const void* __restrict__ Uhr2, const void* __restrict__ Uhr2_b,
    const void* __restrict__ Uhh2, const void* __restrict__ Uhh2_b,
    const void* __restrict__ Wcz, const void* __restrict__ Wcr, const void* __restrict__ Wch,
    const int* __restrict__ rp, const float* __restrict__ sb, const float* __restrict__ rawp,
    float* __restrict__ buf, float* __restrict__ h0_ws, float* __restrict__ ap_ws,
    float* __restrict__ q_ws, float* __restrict__ out, const int* __restrict__ flag){
  const int f32 = flag[0];
  const int b = blockIdx.x, tid = threadIdx.x;
  __shared__ float alpha_lds[PP_];
  __shared__ float h0_lds[NN_];
  __shared__ float h2_lds[NN_];
  __shared__ float ctc_lds[DD_];
  __shared__ float red[12];

  if (tid < 256) h0_lds[tid] = h0_ws[b*256 + tid];

  { // softmax over p = tid (global max cancels in ratio; clamp for safety)
    float raw = gld(vaC_b, 0, f32);
    #pragma unroll
    for (int j2=0;j2<16;j2++) raw += rawp[((size_t)(b*16+j2))*PP_ + tid];
    raw = fminf(fmaxf(raw, -60.f), 60.f);
    float e = __expf(raw) * gld(cmask, b*PP_ + tid, f32);
    alpha_lds[tid] = e;
    float psum = e;
    #pragma unroll
    for (int off=1; off<64; off<<=1) psum += __shfl_xor(psum, off, 64);
    if ((tid & 63) == 0) red[tid >> 6] = psum;
  }
  __syncthreads();
  {
    float S = 0.f;
    #pragma unroll
    for (int w=0; w<9; w++) S += red[w];
    S = fmaxf(S, 1e-30f);
    float inv = rcpf(S);
    float af = alpha_lds[tid]*inv + 1e-10f;
    alpha_lds[tid] = af;
    out[OFF_AL + (t*8+b)*PP_ + tid] = af;
    float apn = ap_ws[b*PP_ + tid] + af;
    ap_ws[b*PP_ + tid] = apn;
    out[OFF_APO + (t*8+b)*PP_ + tid] = apn;
  }
  __syncthreads();

  // ctC[d] = context[b,d,:] . alpha
  for (int d = tid; d < DD_; d += 576){
    float acc;
    if (f32){
      acc = dotf((const float*)context + ((size_t)(b*DD_+d))*PP_, alpha_lds, PP_);
    } else {
      const u16* crow = (const u16*)context + ((size_t)(b*DD_+d))*PP_;
      acc = 0.f;
      #pragma unroll 8
      for (int k=0;k<PP_;k+=8) acc += dot8(*(const uint4*)(crow+k), &alpha_lds[k]);
    }
    ctc_lds[d] = acc;
    if (t < 31) buf[(((size_t)(t+1))*8+b)*DD_ + d] = acc;
    out[OFF_CTC + (t*8+b)*DD_ + d] = acc;
  }
  __syncthreads();

  // GRU2
  if (tid < 256){
    int n = tid;
    float az, ar, ah, cz, cr, ch;
    if (f32){
      az = dotf((const float*)Uhz2 + (size_t)n*256, h0_lds, 256);
      ar = dotf((const float*)Uhr2 + (size_t)n*256, h0_lds, 256);
      ah = dotf((const float*)Uhh2 + (size_t)n*256, h0_lds, 256);
      cz = dotf((const float*)Wcz + (size_t)n*DD_, ctc_lds, DD_);
      cr = dotf((const float*)Wcr + (size_t)n*DD_, ctc_lds, DD_);
      ch = dotf((const float*)Wch + (size_t)n*DD_, ctc_lds, DD_);
    } else {
      const u16* rz = (const u16*)Uhz2 + (size_t)n*256;
      const u16* rr = (const u16*)Uhr2 + (size_t)n*256;
      const u16* rh = (const u16*)Uhh2 + (size_t)n*256;
      az = 0.f; ar = 0.f; ah = 0.f;
      #pragma unroll 4
      for (int k=0;k<256;k+=8){
        az += dot8(*(const uint4*)(rz+k), h0_lds+k);
        ar += dot8(*(const uint4*)(rr+k), h0_lds+k);
        ah += dot8(*(const uint4*)(rh+k), h0_lds+k);
      }
      const u16* wz = (const u16*)Wcz + (size_t)n*DD_;
      const u16* wr = (const u16*)Wcr + (size_t)n*DD_;
      const u16* wh = (const u16*)Wch + (size_t)n*DD_;
      cz = 0.f; cr = 0.f; ch = 0.f;
      for (int k=0;k<680;k+=8){
        cz += dot8(*(const uint4*)(wz+k), ctc_lds+k);
        cr += dot8(*(const uint4*)(wr+k), ctc_lds+k);
        ch += dot8(*(const uint4*)(wh+k), ctc_lds+k);
      }
      cz = dot4(*(const uint2*)(wz+680), ctc_lds+680, cz);
      cr = dot4(*(const uint2*)(wr+680), ctc_lds+680, cr);
      ch = dot4(*(const uint2*)(wh+680), ctc_lds+680, ch);
    }
    float lm = gld(ly_mask, t*8+b, f32);
    float h0v = h0_lds[n];
    float z2 = sigm(az + gld(Uhz2_b, n, f32) + cz);
    float r2 = sigm(ar + gld(Uhr2_b, n, f32) + cr);
    float hc = tanh_c((ah + gld(Uhh2_b, n, f32))*r2 + ch);
    float h2v = z2*h0v + (1.f - z2)*hc;
    h2v = lm*h2v + (1.f - lm)*h0v;
    h2_lds[n] = h2v;
    out[OFF_H2 + (t*8+b)*256 + n] = h2v;
  }
  __syncthreads();

  if (t < 31){
    gru1_tail(b, t+1, f32, h2_lds, Uhz0, Uhr0, Uhh0, WaC, ly_mask, sb, rp, buf,
              h0_ws, q_ws, out, h0_lds);
  }
}

// ---------------- host ----------------

extern "C" void kernel_launch(void* const* d_in, const int* in_sizes, int n_in,
                              void* d_out, int out_size, void* d_ws, size_t ws_size,
                              hipStream_t stream){
  (void)in_sizes; (void)n_in; (void)out_size;
  if (ws_size < WS_NEED) return;   // constant per-deployment; same behavior every call

  const void* remb       = d_in[0];
  const void* re_emb     = d_in[1];
  const void* ly_mask    = d_in[2];
  const void* context    = d_in[3];
  const void* cmask      = d_in[4];
  const void* init_state = d_in[5];
  const void* Wyz_w = d_in[6];  const void* Wyz_b = d_in[7];
  const void* Wyr_w = d_in[8];  const void* Wyr_b = d_in[9];
  const void* Wyh_w = d_in[10]; const void* Wyh_b = d_in[11];
  const void* Uhz0  = d_in[12];
  const void* Uhr0  = d_in[13];
  const void* Uhh0  = d_in[14];
  const void* UaC_w = d_in[15]; const void* UaC_b = d_in[16];
  const void* WaC_w = d_in[17];
  const void* QC_w  = d_in[18];
  const void* UfC_w = d_in[19]; const void* UfC_b = d_in[20];
  const void* vaC_w = d_in[21]; const void* vaC_b = d_in[22];
  const void* Uhz2  = d_in[23]; const void* Uhz2_b = d_in[24];
  const void* Uhr2  = d_in[25]; const void* Uhr2_b = d_in[26];
  const void* Uhh2  = d_in[27]; const void* Uhh2_b = d_in[28];
  const void* Wcz   = d_in[29];
  const void* Wcr   = d_in[30];
  const void* Wch   = d_in[31];
  const int*  rp    = (const int*)d_in[32];

  char* ws = (char*)d_ws;
  float* pctxs = (float*)(ws + OFF_PCTX);
  float* sb    = (float*)(ws + OFF_SB);
  float* FKt   = (float*)(ws + OFF_FKT);
  float* buf   = (float*)(ws + OFF_BUF);
  float* rawp  = (float*)(ws + OFF_RAWP);
  float* h_ws  = (float*)(ws + OFF_H);
  float* h0_ws = (float*)(ws + OFF_H0);
  float* ap_ws = (float*)(ws + OFF_AP);
  float* q_ws  = (float*)(ws + OFF_QWS);
  int*   flag  = (int*)  (ws + OFF_FLG);
  float* out   = (float*)d_out;   // reference output dtype is float32

  k_detect<<<1, 256, 0, stream>>>((const u16*)context, flag);
  k_init<<<256, 256, 0, stream>>>(buf, ap_ws, h_ws, init_state, flag);
  k_sb  <<<768, 256, 0, stream>>>(remb, re_emb, Wyz_w, Wyz_b, Wyr_w, Wyr_b, Wyh_w, Wyh_b, sb, flag);
  k_fk  <<<18,  256, 0, stream>>>(QC_w, UfC_w, FKt, flag);
  k_pctx<<<576, 256, 0, stream>>>(context, UaC_w, UaC_b, UfC_b, pctxs, flag);
  k_stepA0<<<8, 576, 0, stream>>>(ly_mask, Uhz0, Uhr0, Uhh0, WaC_w, rp, sb, buf, h_ws,
                                  h0_ws, q_ws, out, flag);
  for (int t = 0; t < 32; t++){
    k_stepB<<<128, 256, 0, stream>>>(t, pctxs, FKt, vaC_w, q_ws, ap_ws, rawp, flag);
    k_stepC<<<8, 576, 0, stream>>>(t, ly_mask, context, cmask,
                                   Uhz0, Uhr0, Uhh0, WaC_w, vaC_b,
                                   Uhz2, Uhz2_b, Uhr2, Uhr2_b, Uhh2, Uhh2_b,
                                   Wcz, Wcr, Wch, rp, sb, rawp,
                                   buf, h0_ws, ap_ws, q_ws, out, flag);
  }
}